// Round 1
// 729.560 us; speedup vs baseline: 1.6226x; 1.6226x over previous
//
#include <hip/hip_runtime.h>
#include <math.h>

#define B_   4
#define T_   512
#define TAU_ 512
#define L_   1024
#define DM_  1024
#define H_   16
#define D_   64

typedef short  s16x8 __attribute__((ext_vector_type(8)));   // 8 bf16 MFMA frag
typedef ushort u16x4 __attribute__((ext_vector_type(4)));
typedef float  f32x4 __attribute__((ext_vector_type(4)));

__device__ __forceinline__ ushort f2bf(float x) {   // RNE float->bf16 bits
  uint u = __float_as_uint(x);
  u += 0x7fffu + ((u >> 16) & 1u);
  return (ushort)(u >> 16);
}
// XOR-swizzle for bf16 [rows][64] LDS tiles (128B rows): flip 16B slot by row&7
__device__ __forceinline__ int sw64(int row, int col) {
  return row * 64 + (col ^ ((row & 7) << 3));
}

// ---------------------------------------------------------------------------
// LayerNorm over concat(memory, inputs) rows. One block per (b, l) row.
// ---------------------------------------------------------------------------
__global__ __launch_bounds__(256) void ln_concat_kernel(
    const float* __restrict__ inp, const float* __restrict__ mem,
    const float* __restrict__ gamma, const float* __restrict__ beta,
    float* __restrict__ xn) {
  int row = blockIdx.x;              // b*L + l
  int b = row >> 10, l = row & 1023;
  const float* src = (l < TAU_)
      ? mem + ((size_t)b * TAU_ + l) * DM_
      : inp + ((size_t)b * T_ + (l - TAU_)) * DM_;
  int t = threadIdx.x;
  float4 v = *(const float4*)(src + t * 4);
  float s  = v.x + v.y + v.z + v.w;
  float s2 = v.x * v.x + v.y * v.y + v.z * v.z + v.w * v.w;
#pragma unroll
  for (int off = 32; off > 0; off >>= 1) {
    s  += __shfl_down(s, off);
    s2 += __shfl_down(s2, off);
  }
  __shared__ float red[8];
  __shared__ float stat[2];
  int wid = t >> 6;
  if ((t & 63) == 0) { red[wid * 2] = s; red[wid * 2 + 1] = s2; }
  __syncthreads();
  if (t == 0) {
    float ts  = red[0] + red[2] + red[4] + red[6];
    float ts2 = red[1] + red[3] + red[5] + red[7];
    float mu  = ts * (1.0f / DM_);
    float var = ts2 * (1.0f / DM_) - mu * mu;
    stat[0] = mu;
    stat[1] = 1.0f / sqrtf(var + 1e-5f);
  }
  __syncthreads();
  float mu = stat[0], rstd = stat[1];
  float4 g  = *(const float4*)(gamma + t * 4);
  float4 be = *(const float4*)(beta  + t * 4);
  float4 o;
  o.x = (v.x - mu) * rstd * g.x + be.x;
  o.y = (v.y - mu) * rstd * g.y + be.y;
  o.z = (v.z - mu) * rstd * g.z + be.z;
  o.w = (v.w - mu) * rstd * g.w + be.w;
  *(float4*)(xn + (size_t)row * DM_ + t * 4) = o;
}

// ---------------------------------------------------------------------------
// phi[m][c]: m in [0,1024), pos = 1023-m; c<512 -> sin(pos*invf[c]),
// else cos(pos*invf[c-512]); invf[c] = 10000^(-2c/1024)
// ---------------------------------------------------------------------------
__global__ __launch_bounds__(256) void phi_kernel(float* __restrict__ phi) {
  int idx = blockIdx.x * 256 + threadIdx.x;   // 0 .. 1M-1
  int m = idx >> 10, c = idx & 1023;
  float p = (float)(1023 - m);
  int cc = (c < 512) ? c : c - 512;
  float invf = __expf(-((float)(2 * cc) * (1.0f / 1024.0f)) * 9.210340371976184f);
  float a = p * invf;
  phi[idx] = (c < 512) ? sinf(a) : cosf(a);
}

// ---------------------------------------------------------------------------
// Generic NT GEMM: C[M,N] = A[M,K] * B[N,K]^T, all row-major fp32.
// ---------------------------------------------------------------------------
#define BM 128
#define BN 128
#define BK 16
__global__ __launch_bounds__(256) void gemm_nt(
    const float* __restrict__ A, const float* __restrict__ B,
    float* __restrict__ C, int M, int N, int K) {
  __shared__ float As[BK][BM + 4];
  __shared__ float Bs[BK][BN + 4];
  int t  = threadIdx.x;
  int tx = t & 15, ty = t >> 4;
  int m0 = blockIdx.y * BM, n0 = blockIdx.x * BN;
  float acc[8][8];
#pragma unroll
  for (int i = 0; i < 8; ++i)
#pragma unroll
    for (int j = 0; j < 8; ++j) acc[i][j] = 0.0f;

  for (int kt = 0; kt < K; kt += BK) {
#pragma unroll
    for (int q = 0; q < 2; ++q) {
      int f   = t + q * 256;
      int row = f >> 2;
      int c4  = (f & 3) * 4;
      float4 av = *(const float4*)(A + (size_t)(m0 + row) * K + kt + c4);
      As[c4 + 0][row] = av.x; As[c4 + 1][row] = av.y;
      As[c4 + 2][row] = av.z; As[c4 + 3][row] = av.w;
      float4 bv = *(const float4*)(B + (size_t)(n0 + row) * K + kt + c4);
      Bs[c4 + 0][row] = bv.x; Bs[c4 + 1][row] = bv.y;
      Bs[c4 + 2][row] = bv.z; Bs[c4 + 3][row] = bv.w;
    }
    __syncthreads();
#pragma unroll
    for (int kk = 0; kk < BK; ++kk) {
      float a[8], b[8];
      *(float4*)(a)     = *(const float4*)&As[kk][ty * 4];
      *(float4*)(a + 4) = *(const float4*)&As[kk][64 + ty * 4];
      *(float4*)(b)     = *(const float4*)&Bs[kk][tx * 4];
      *(float4*)(b + 4) = *(const float4*)&Bs[kk][64 + tx * 4];
#pragma unroll
      for (int i = 0; i < 8; ++i)
#pragma unroll
        for (int j = 0; j < 8; ++j) acc[i][j] += a[i] * b[j];
    }
    __syncthreads();
  }
#pragma unroll
  for (int i = 0; i < 8; ++i) {
    int m = m0 + ((i < 4) ? (ty * 4 + i) : (64 + ty * 4 + i - 4));
    float4 v0 = make_float4(acc[i][0], acc[i][1], acc[i][2], acc[i][3]);
    float4 v1 = make_float4(acc[i][4], acc[i][5], acc[i][6], acc[i][7]);
    *(float4*)(C + (size_t)m * N + n0 + tx * 4)      = v0;
    *(float4*)(C + (size_t)m * N + n0 + 64 + tx * 4) = v1;
  }
}

// ---------------------------------------------------------------------------
// MFMA bf16 flash attention with rel-shift.
// Block = (b, h, 64-row i-block). 4 waves; wave w owns i-rows [i0+16w, +16).
// Per j-tile (64): QK^T (8 mfma) ; P = (q+v)·R over 80 m-cols (10 mfma,
// i-independent so MFMA-legal; rel-shift applied as shifted LDS read);
// wave-parallel online softmax in regs; PV (8 mfma) via bf16 P + V^T tiles.
// mfma_f32_16x16x32_bf16 layouts: A row=l&15,k=8*(l>>4)+e ; B col=l&15,
// k=8*(l>>4)+e ; C col=l&15,row=4*(l>>4)+reg  (guide §3, m89/m97-verified).
// ---------------------------------------------------------------------------
__global__ __launch_bounds__(256) void attn_mfma_kernel(
    const float* __restrict__ qkv, const float* __restrict__ Rm,
    const float* __restrict__ uvar, const float* __restrict__ vvar,
    float* __restrict__ attn) {
  __shared__ __attribute__((aligned(16))) ushort Ks[64 * 64];    // K  [j][d] bf16, swizzled
  __shared__ __attribute__((aligned(16))) ushort Vt[64 * 64];    // V^T[d][j] bf16, swizzled
  __shared__ __attribute__((aligned(16))) ushort Rs[128 * 64];   // R  [m][d] bf16, swizzled
  __shared__ __attribute__((aligned(16))) float  Ps[4][16 * 84]; // wave-private P f32
  __shared__ __attribute__((aligned(16))) ushort Pp[4][16 * 64]; // wave-private P bf16, swz

  int t   = threadIdx.x;
  int w   = t >> 6;          // wave 0..3
  int lw  = t & 63;
  int g   = lw >> 4;         // k-group 0..3
  int low = lw & 15;

  int bid = blockIdx.x;
  int bi  = bid & 7;
  int h   = (bid >> 3) & 15;
  int b   = bid >> 7;
  int i0  = bi * 64;
  int lb_w = 48 - 16 * w;    // wave's P m-window base within Rs

  // Q fragments, loaded once: A-frag row = low  ->  query i0+16w+low
  int iq = i0 + 16 * w + low;
  s16x8 qu[2], qv[2];
  {
    const float* qrow = qkv + ((size_t)(b * L_ + TAU_ + iq) * 3072) + h * 64;
    const float* ur = uvar + h * 64;
    const float* vr = vvar + h * 64;
#pragma unroll
    for (int kc = 0; kc < 2; ++kc) {
      int dbase = kc * 32 + 8 * g;
#pragma unroll
      for (int e = 0; e < 8; ++e) {
        float q = qrow[dbase + e];
        qu[kc][e] = (short)f2bf(q + ur[dbase + e]);
        qv[kc][e] = (short)f2bf(q + vr[dbase + e]);
      }
    }
  }

  f32x4 O[4] = {};
  float mreg[4] = {-INFINITY, -INFINITY, -INFINITY, -INFINITY};
  float lreg[4] = {0.f, 0.f, 0.f, 0.f};

  int ntiles = 9 + bi;       // covers j <= TAU + i0 + 63 exactly
  for (int tile = 0; tile < ntiles; ++tile) {
    int j0 = tile * 64;
    __syncthreads();         // previous tile's LDS reads done
    // ---- stage K tile (64 j x 64 d) ----
#pragma unroll
    for (int q8 = 0; q8 < 4; ++q8) {
      int f = t + q8 * 256;
      int row = f >> 4, c4 = (f & 15) * 4;
      float4 kv = *(const float4*)(qkv +
          ((size_t)(b * L_ + j0 + row) * 3072) + 1024 + h * 64 + c4);
      u16x4 pk = { f2bf(kv.x), f2bf(kv.y), f2bf(kv.z), f2bf(kv.w) };
      *(u16x4*)&Ks[sw64(row, c4)] = pk;
    }
    // ---- stage V transposed (Vt[d][j]) ----
#pragma unroll
    for (int q8 = 0; q8 < 4; ++q8) {
      int f = t + q8 * 256;
      int j = f >> 4, c4 = (f & 15) * 4;
      float4 vv = *(const float4*)(qkv +
          ((size_t)(b * L_ + j0 + j) * 3072) + 2048 + h * 64 + c4);
      Vt[sw64(c4 + 0, j)] = f2bf(vv.x);
      Vt[sw64(c4 + 1, j)] = f2bf(vv.y);
      Vt[sw64(c4 + 2, j)] = f2bf(vv.z);
      Vt[sw64(c4 + 3, j)] = f2bf(vv.w);
    }
    // ---- stage R tile (128 m-rows) : m = mb + row, clamped ----
    int mb = j0 + 448 - i0;
#pragma unroll
    for (int q8 = 0; q8 < 8; ++q8) {
      int f = t + q8 * 256;
      int row = f >> 4, c4 = (f & 15) * 4;
      int m = mb + row;
      m = (m < 0) ? 0 : ((m > 1023) ? 1023 : m);
      float4 rv = *(const float4*)(Rm + (size_t)m * 1024 + h * 64 + c4);
      u16x4 pk = { f2bf(rv.x), f2bf(rv.y), f2bf(rv.z), f2bf(rv.w) };
      *(u16x4*)&Rs[sw64(row, c4)] = pk;
    }
    __syncthreads();
    // ---- QK^T : s[jt] over 4 j-subtiles ----
    f32x4 s[4] = {};
#pragma unroll
    for (int jt = 0; jt < 4; ++jt) {
#pragma unroll
      for (int kc = 0; kc < 2; ++kc) {
        s16x8 kb = *(const s16x8*)&Ks[sw64(jt * 16 + low, kc * 32 + 8 * g)];
        s[jt] = __builtin_amdgcn_mfma_f32_16x16x32_bf16(qu[kc], kb, s[jt], 0, 0, 0);
      }
    }
    // ---- P = (q+v)·R over 80 m-cols (i-independent) ----
    f32x4 p[5] = {};
#pragma unroll
    for (int mt = 0; mt < 5; ++mt) {
#pragma unroll
      for (int kc = 0; kc < 2; ++kc) {
        s16x8 rb = *(const s16x8*)&Rs[sw64(lb_w + mt * 16 + low, kc * 32 + 8 * g)];
        p[mt] = __builtin_amdgcn_mfma_f32_16x16x32_bf16(qv[kc], rb, p[mt], 0, 0, 0);
      }
    }
    // spill P to wave-private LDS for the rel-shift cross-lane read
#pragma unroll
    for (int mt = 0; mt < 5; ++mt)
#pragma unroll
      for (int r = 0; r < 4; ++r)
        Ps[w][(4 * g + r) * 84 + mt * 16 + low] = p[mt][r];
    asm volatile("s_waitcnt lgkmcnt(0)" ::: "memory");
    // combine with shifted P, scale, mask
#pragma unroll
    for (int jt = 0; jt < 4; ++jt) {
#pragma unroll
      for (int r = 0; r < 4; ++r) {
        int iL = 4 * g + r;
        int jj = jt * 16 + low;
        float pos = Ps[w][iL * 84 + jj + 15 - iL];   // m = j + 511 - i
        float sc = (s[jt][r] + pos) * 0.125f;
        s[jt][r] = ((j0 + jj) <= (TAU_ + i0 + 16 * w + iL)) ? sc : -1e30f;
      }
    }
    // ---- wave-parallel online softmax (row = 4g+r lives on 16 lanes) ----
#pragma unroll
    for (int r = 0; r < 4; ++r) {
      float mx = fmaxf(fmaxf(s[0][r], s[1][r]), fmaxf(s[2][r], s[3][r]));
      mx = fmaxf(mx, __shfl_xor(mx, 1));
      mx = fmaxf(mx, __shfl_xor(mx, 2));
      mx = fmaxf(mx, __shfl_xor(mx, 4));
      mx = fmaxf(mx, __shfl_xor(mx, 8));
      float mn = fmaxf(mreg[r], mx);
      float alpha = __expf(mreg[r] - mn);
      mreg[r] = mn;
      float sum = 0.f;
#pragma unroll
      for (int jt = 0; jt < 4; ++jt) {
        float pe = __expf(s[jt][r] - mn);
        s[jt][r] = pe;
        sum += pe;
      }
      sum += __shfl_xor(sum, 1);
      sum += __shfl_xor(sum, 2);
      sum += __shfl_xor(sum, 4);
      sum += __shfl_xor(sum, 8);
      lreg[r] = lreg[r] * alpha + sum;
      O[0][r] *= alpha; O[1][r] *= alpha; O[2][r] *= alpha; O[3][r] *= alpha;
    }
    // P -> bf16 LDS (layout change for PV A-frags)
#pragma unroll
    for (int jt = 0; jt < 4; ++jt)
#pragma unroll
      for (int r = 0; r < 4; ++r)
        Pp[w][sw64(4 * g + r, jt * 16 + low)] = f2bf(s[jt][r]);
    asm volatile("s_waitcnt lgkmcnt(0)" ::: "memory");
    // ---- PV : O[dt] += P · V ----
    s16x8 pa0 = *(const s16x8*)&Pp[w][sw64(low, 8 * g)];
    s16x8 pa1 = *(const s16x8*)&Pp[w][sw64(low, 32 + 8 * g)];
#pragma unroll
    for (int dt = 0; dt < 4; ++dt) {
      s16x8 v0 = *(const s16x8*)&Vt[sw64(dt * 16 + low, 8 * g)];
      s16x8 v1 = *(const s16x8*)&Vt[sw64(dt * 16 + low, 32 + 8 * g)];
      O[dt] = __builtin_amdgcn_mfma_f32_16x16x32_bf16(pa0, v0, O[dt], 0, 0, 0);
      O[dt] = __builtin_amdgcn_mfma_f32_16x16x32_bf16(pa1, v1, O[dt], 0, 0, 0);
    }
  }
  // epilogue: normalize and store
  float inv[4];
#pragma unroll
  for (int r = 0; r < 4; ++r) inv[r] = 1.0f / lreg[r];
#pragma unroll
  for (int dt = 0; dt < 4; ++dt)
#pragma unroll
    for (int r = 0; r < 4; ++r)
      attn[((size_t)(b * T_ + i0 + 16 * w + 4 * g + r)) * 1024 +
           h * 64 + dt * 16 + low] = O[dt][r] * inv[r];
}

// ---------------------------------------------------------------------------
extern "C" void kernel_launch(void* const* d_in, const int* in_sizes, int n_in,
                              void* d_out, int out_size, void* d_ws, size_t ws_size,
                              hipStream_t stream) {
  const float* inputs = (const float*)d_in[0];
  const float* memory = (const float*)d_in[1];
  const float* w_qkv  = (const float*)d_in[2];
  const float* w_pos  = (const float*)d_in[3];
  const float* w_out  = (const float*)d_in[4];
  const float* uvar   = (const float*)d_in[5];
  const float* vvar   = (const float*)d_in[6];
  const float* gamma  = (const float*)d_in[7];
  const float* beta   = (const float*)d_in[8];
  float* out = (float*)d_out;

  float* ws   = (float*)d_ws;
  float* qkv  = ws;                          // 4096*3072 floats
  float* xn   = qkv + (size_t)4096 * 3072;   // 4096*1024
  float* phi  = xn  + (size_t)4096 * 1024;   // 1024*1024
  float* Rm   = phi + (size_t)1024 * 1024;   // 1024*1024
  float* attn = xn;                          // reuse xn after QKV GEMM

  ln_concat_kernel<<<B_ * L_, 256, 0, stream>>>(inputs, memory, gamma, beta, xn);
  phi_kernel<<<(L_ * DM_) / 256, 256, 0, stream>>>(phi);
  gemm_nt<<<dim3(3072 / BN, 4096 / BM), 256, 0, stream>>>(xn, w_qkv, qkv, 4096, 3072, 1024);
  gemm_nt<<<dim3(1024 / BN, 1024 / BM), 256, 0, stream>>>(phi, w_pos, Rm, 1024, 1024, 1024);
  attn_mfma_kernel<<<dim3(B_ * H_ * 8), 256, 0, stream>>>(qkv, Rm, uvar, vvar, attn);
  gemm_nt<<<dim3(1024 / BN, 2048 / BM), 256, 0, stream>>>(attn, w_out, out, 2048, 1024, 1024);
}

// Round 2
// 306.227 us; speedup vs baseline: 3.8657x; 2.3824x over previous
//
#include <hip/hip_runtime.h>
#include <math.h>

#define B_   4
#define T_   512
#define TAU_ 512
#define L_   1024
#define DM_  1024
#define H_   16
#define D_   64

typedef short  s16x8 __attribute__((ext_vector_type(8)));   // 8 bf16 MFMA frag
typedef ushort u16x4 __attribute__((ext_vector_type(4)));
typedef float  f32x4 __attribute__((ext_vector_type(4)));

__device__ __forceinline__ ushort f2bf(float x) {   // RNE float->bf16 bits
  uint u = __float_as_uint(x);
  u += 0x7fffu + ((u >> 16) & 1u);
  return (ushort)(u >> 16);
}
// XOR-swizzle for bf16 [rows][64] LDS tiles (128B rows): flip 16B slot by row&7
__device__ __forceinline__ int sw64(int row, int col) {
  return row * 64 + (col ^ ((row & 7) << 3));
}

// ---------------------------------------------------------------------------
// LayerNorm over concat(memory, inputs) rows -> bf16 output. Block per row.
// ---------------------------------------------------------------------------
__global__ __launch_bounds__(256) void ln_concat_kernel(
    const float* __restrict__ inp, const float* __restrict__ mem,
    const float* __restrict__ gamma, const float* __restrict__ beta,
    ushort* __restrict__ xn) {
  int row = blockIdx.x;              // b*L + l
  int b = row >> 10, l = row & 1023;
  const float* src = (l < TAU_)
      ? mem + ((size_t)b * TAU_ + l) * DM_
      : inp + ((size_t)b * T_ + (l - TAU_)) * DM_;
  int t = threadIdx.x;
  float4 v = *(const float4*)(src + t * 4);
  float s  = v.x + v.y + v.z + v.w;
  float s2 = v.x * v.x + v.y * v.y + v.z * v.z + v.w * v.w;
#pragma unroll
  for (int off = 32; off > 0; off >>= 1) {
    s  += __shfl_down(s, off);
    s2 += __shfl_down(s2, off);
  }
  __shared__ float red[8];
  __shared__ float stat[2];
  int wid = t >> 6;
  if ((t & 63) == 0) { red[wid * 2] = s; red[wid * 2 + 1] = s2; }
  __syncthreads();
  if (t == 0) {
    float ts  = red[0] + red[2] + red[4] + red[6];
    float ts2 = red[1] + red[3] + red[5] + red[7];
    float mu  = ts * (1.0f / DM_);
    float var = ts2 * (1.0f / DM_) - mu * mu;
    stat[0] = mu;
    stat[1] = 1.0f / sqrtf(var + 1e-5f);
  }
  __syncthreads();
  float mu = stat[0], rstd = stat[1];
  float4 g  = *(const float4*)(gamma + t * 4);
  float4 be = *(const float4*)(beta  + t * 4);
  u16x4 o;
  o[0] = f2bf((v.x - mu) * rstd * g.x + be.x);
  o[1] = f2bf((v.y - mu) * rstd * g.y + be.y);
  o[2] = f2bf((v.z - mu) * rstd * g.z + be.z);
  o[3] = f2bf((v.w - mu) * rstd * g.w + be.w);
  *(u16x4*)(xn + (size_t)row * DM_ + t * 4) = o;
}

// ---------------------------------------------------------------------------
// phi[m][c] in bf16: m in [0,1024), pos = 1023-m; c<512 -> sin, else cos.
// ---------------------------------------------------------------------------
__global__ __launch_bounds__(256) void phi_kernel(ushort* __restrict__ phi) {
  int idx = blockIdx.x * 256 + threadIdx.x;   // 0 .. 1M-1
  int m = idx >> 10, c = idx & 1023;
  float p = (float)(1023 - m);
  int cc = (c < 512) ? c : c - 512;
  float invf = __expf(-((float)(2 * cc) * (1.0f / 1024.0f)) * 9.210340371976184f);
  float a = p * invf;
  phi[idx] = f2bf((c < 512) ? sinf(a) : cosf(a));
}

// ---------------------------------------------------------------------------
// fp32 -> bf16 cast, float4-vectorized. n4 = n/4.
// ---------------------------------------------------------------------------
__global__ __launch_bounds__(256) void cast_bf16_kernel(
    const float* __restrict__ in, ushort* __restrict__ out, int n4) {
  int i = blockIdx.x * 256 + threadIdx.x;
  if (i >= n4) return;
  float4 v = *(const float4*)(in + (size_t)i * 4);
  u16x4 o = { f2bf(v.x), f2bf(v.y), f2bf(v.z), f2bf(v.w) };
  *(u16x4*)(out + (size_t)i * 4) = o;
}

// ---------------------------------------------------------------------------
// bf16 MFMA NT GEMM: C[M,N]fp32 = A[M,K]bf16 * B[N,K]bf16^T, row-major.
// m97 structure (guide §5 ladder step 3): 128x128 tile, BK=32, 4 waves in
// 2x2, 4x4 16x16x32 fragments per wave, global_load_lds width-16 staging,
// 2 barriers per K-step. LDS [128][32]bf16 linear; conflicts fixed by the
// both-sides XOR swizzle (rule #21): 16B k-slot ^= (row>>1)&3 applied to the
// GLOBAL source address at stage time and to the ds_read_b128 at frag time.
// M,N multiples of 128; K multiple of 32.
// ---------------------------------------------------------------------------
__global__ __launch_bounds__(256) void gemm_nt_bf16(
    const ushort* __restrict__ A, const ushort* __restrict__ B,
    float* __restrict__ C, int M, int N, int K) {
  __shared__ __attribute__((aligned(16))) ushort As[128 * 32];
  __shared__ __attribute__((aligned(16))) ushort Bs[128 * 32];
  int t = threadIdx.x;
  int w = t >> 6, lane = t & 63, g = lane >> 4, low = lane & 15;
  int wr = w >> 1, wc = w & 1;               // wave 2x2 grid, 64x64 each
  int m0 = blockIdx.y * 128, n0 = blockIdx.x * 128;
  f32x4 acc[4][4] = {};

  for (int kt = 0; kt < K; kt += 32) {
    __syncthreads();                         // prev-iter LDS reads done
#pragma unroll
    for (int q = 0; q < 2; ++q) {
      int f = t + q * 256;                   // chunk 0..511 (16B each)
      int row = f >> 2;
      int gslot = (f & 3) ^ ((row >> 1) & 3);
      const ushort* ga = A + (size_t)(m0 + row) * K + kt + gslot * 8;
      const ushort* gb = B + (size_t)(n0 + row) * K + kt + gslot * 8;
      // LDS dest is wave-uniform base + lane*16 (m104): chunk q*256+w*64
      __builtin_amdgcn_global_load_lds(
          (const __attribute__((address_space(1))) void*)ga,
          (__attribute__((address_space(3))) void*)&As[(q * 256 + w * 64) * 8],
          16, 0, 0);
      __builtin_amdgcn_global_load_lds(
          (const __attribute__((address_space(1))) void*)gb,
          (__attribute__((address_space(3))) void*)&Bs[(q * 256 + w * 64) * 8],
          16, 0, 0);
    }
    __syncthreads();                         // vmcnt(0) drain: tiles ready

    s16x8 af[4], bfr[4];
#pragma unroll
    for (int mi = 0; mi < 4; ++mi) {
      int row = wr * 64 + mi * 16 + low;
      af[mi] = *(const s16x8*)&As[row * 32 + ((g ^ ((row >> 1) & 3)) * 8)];
    }
#pragma unroll
    for (int ni = 0; ni < 4; ++ni) {
      int col = wc * 64 + ni * 16 + low;
      bfr[ni] = *(const s16x8*)&Bs[col * 32 + ((g ^ ((col >> 1) & 3)) * 8)];
    }
#pragma unroll
    for (int mi = 0; mi < 4; ++mi)
#pragma unroll
      for (int ni = 0; ni < 4; ++ni)
        acc[mi][ni] = __builtin_amdgcn_mfma_f32_16x16x32_bf16(
            af[mi], bfr[ni], acc[mi][ni], 0, 0, 0);
  }
  // epilogue: C row = 4g+r, col = low within each 16x16 (verified layout)
#pragma unroll
  for (int mi = 0; mi < 4; ++mi)
#pragma unroll
    for (int ni = 0; ni < 4; ++ni)
#pragma unroll
      for (int r = 0; r < 4; ++r) {
        int m = m0 + wr * 64 + mi * 16 + 4 * g + r;
        int n = n0 + wc * 64 + ni * 16 + low;
        C[(size_t)m * N + n] = acc[mi][ni][r];
      }
}

// ---------------------------------------------------------------------------
// MFMA bf16 flash attention with rel-shift (unchanged except bf16 output).
// ---------------------------------------------------------------------------
__global__ __launch_bounds__(256) void attn_mfma_kernel(
    const float* __restrict__ qkv, const float* __restrict__ Rm,
    const float* __restrict__ uvar, const float* __restrict__ vvar,
    ushort* __restrict__ attn) {
  __shared__ __attribute__((aligned(16))) ushort Ks[64 * 64];    // K  [j][d] bf16, swizzled
  __shared__ __attribute__((aligned(16))) ushort Vt[64 * 64];    // V^T[d][j] bf16, swizzled
  __shared__ __attribute__((aligned(16))) ushort Rs[128 * 64];   // R  [m][d] bf16, swizzled
  __shared__ __attribute__((aligned(16))) float  Ps[4][16 * 84]; // wave-private P f32
  __shared__ __attribute__((aligned(16))) ushort Pp[4][16 * 64]; // wave-private P bf16, swz

  int t   = threadIdx.x;
  int w   = t >> 6;          // wave 0..3
  int lw  = t & 63;
  int g   = lw >> 4;         // k-group 0..3
  int low = lw & 15;

  int bid = blockIdx.x;
  int bi  = bid & 7;
  int h   = (bid >> 3) & 15;
  int b   = bid >> 7;
  int i0  = bi * 64;
  int lb_w = 48 - 16 * w;    // wave's P m-window base within Rs

  // Q fragments, loaded once: A-frag row = low  ->  query i0+16w+low
  int iq = i0 + 16 * w + low;
  s16x8 qu[2], qv[2];
  {
    const float* qrow = qkv + ((size_t)(b * L_ + TAU_ + iq) * 3072) + h * 64;
    const float* ur = uvar + h * 64;
    const float* vr = vvar + h * 64;
#pragma unroll
    for (int kc = 0; kc < 2; ++kc) {
      int dbase = kc * 32 + 8 * g;
#pragma unroll
      for (int e = 0; e < 8; ++e) {
        float q = qrow[dbase + e];
        qu[kc][e] = (short)f2bf(q + ur[dbase + e]);
        qv[kc][e] = (short)f2bf(q + vr[dbase + e]);
      }
    }
  }

  f32x4 O[4] = {};
  float mreg[4] = {-INFINITY, -INFINITY, -INFINITY, -INFINITY};
  float lreg[4] = {0.f, 0.f, 0.f, 0.f};

  int ntiles = 9 + bi;       // covers j <= TAU + i0 + 63 exactly
  for (int tile = 0; tile < ntiles; ++tile) {
    int j0 = tile * 64;
    __syncthreads();         // previous tile's LDS reads done
    // ---- stage K tile (64 j x 64 d) ----
#pragma unroll
    for (int q8 = 0; q8 < 4; ++q8) {
      int f = t + q8 * 256;
      int row = f >> 4, c4 = (f & 15) * 4;
      float4 kv = *(const float4*)(qkv +
          ((size_t)(b * L_ + j0 + row) * 3072) + 1024 + h * 64 + c4);
      u16x4 pk = { f2bf(kv.x), f2bf(kv.y), f2bf(kv.z), f2bf(kv.w) };
      *(u16x4*)&Ks[sw64(row, c4)] = pk;
    }
    // ---- stage V transposed (Vt[d][j]) ----
#pragma unroll
    for (int q8 = 0; q8 < 4; ++q8) {
      int f = t + q8 * 256;
      int j = f >> 4, c4 = (f & 15) * 4;
      float4 vv = *(const float4*)(qkv +
          ((size_t)(b * L_ + j0 + j) * 3072) + 2048 + h * 64 + c4);
      Vt[sw64(c4 + 0, j)] = f2bf(vv.x);
      Vt[sw64(c4 + 1, j)] = f2bf(vv.y);
      Vt[sw64(c4 + 2, j)] = f2bf(vv.z);
      Vt[sw64(c4 + 3, j)] = f2bf(vv.w);
    }
    // ---- stage R tile (128 m-rows) : m = mb + row, clamped ----
    int mb = j0 + 448 - i0;
#pragma unroll
    for (int q8 = 0; q8 < 8; ++q8) {
      int f = t + q8 * 256;
      int row = f >> 4, c4 = (f & 15) * 4;
      int m = mb + row;
      m = (m < 0) ? 0 : ((m > 1023) ? 1023 : m);
      float4 rv = *(const float4*)(Rm + (size_t)m * 1024 + h * 64 + c4);
      u16x4 pk = { f2bf(rv.x), f2bf(rv.y), f2bf(rv.z), f2bf(rv.w) };
      *(u16x4*)&Rs[sw64(row, c4)] = pk;
    }
    __syncthreads();
    // ---- QK^T : s[jt] over 4 j-subtiles ----
    f32x4 s[4] = {};
#pragma unroll
    for (int jt = 0; jt < 4; ++jt) {
#pragma unroll
      for (int kc = 0; kc < 2; ++kc) {
        s16x8 kb = *(const s16x8*)&Ks[sw64(jt * 16 + low, kc * 32 + 8 * g)];
        s[jt] = __builtin_amdgcn_mfma_f32_16x16x32_bf16(qu[kc], kb, s[jt], 0, 0, 0);
      }
    }
    // ---- P = (q+v)·R over 80 m-cols (i-independent) ----
    f32x4 p[5] = {};
#pragma unroll
    for (int mt = 0; mt < 5; ++mt) {
#pragma unroll
      for (int kc = 0; kc < 2; ++kc) {
        s16x8 rb = *(const s16x8*)&Rs[sw64(lb_w + mt * 16 + low, kc * 32 + 8 * g)];
        p[mt] = __builtin_amdgcn_mfma_f32_16x16x32_bf16(qv[kc], rb, p[mt], 0, 0, 0);
      }
    }
    // spill P to wave-private LDS for the rel-shift cross-lane read
#pragma unroll
    for (int mt = 0; mt < 5; ++mt)
#pragma unroll
      for (int r = 0; r < 4; ++r)
        Ps[w][(4 * g + r) * 84 + mt * 16 + low] = p[mt][r];
    asm volatile("s_waitcnt lgkmcnt(0)" ::: "memory");
    // combine with shifted P, scale, mask
#pragma unroll
    for (int jt = 0; jt < 4; ++jt) {
#pragma unroll
      for (int r = 0; r < 4; ++r) {
        int iL = 4 * g + r;
        int jj = jt * 16 + low;
        float pos = Ps[w][iL * 84 + jj + 15 - iL];   // m = j + 511 - i
        float sc = (s[jt][r] + pos) * 0.125f;
        s[jt][r] = ((j0 + jj) <= (TAU_ + i0 + 16 * w + iL)) ? sc : -1e30f;
      }
    }
    // ---- wave-parallel online softmax (row = 4g+r lives on 16 lanes) ----
#pragma unroll
    for (int r = 0; r < 4; ++r) {
      float mx = fmaxf(fmaxf(s[0][r], s[1][r]), fmaxf(s[2][r], s[3][r]));
      mx = fmaxf(mx, __shfl_xor(mx, 1));
      mx = fmaxf(mx, __shfl_xor(mx, 2));
      mx = fmaxf(mx, __shfl_xor(mx, 4));
      mx = fmaxf(mx, __shfl_xor(mx, 8));
      float mn = fmaxf(mreg[r], mx);
      float alpha = __expf(mreg[r] - mn);
      mreg[r] = mn;
      float sum = 0.f;
#pragma unroll
      for (int jt = 0; jt < 4; ++jt) {
        float pe = __expf(s[jt][r] - mn);
        s[jt][r] = pe;
        sum += pe;
      }
      sum += __shfl_xor(sum, 1);
      sum += __shfl_xor(sum, 2);
      sum += __shfl_xor(sum, 4);
      sum += __shfl_xor(sum, 8);
      lreg[r] = lreg[r] * alpha + sum;
      O[0][r] *= alpha; O[1][r] *= alpha; O[2][r] *= alpha; O[3][r] *= alpha;
    }
    // P -> bf16 LDS (layout change for PV A-frags)
#pragma unroll
    for (int jt = 0; jt < 4; ++jt)
#pragma unroll
      for (int r = 0; r < 4; ++r)
        Pp[w][sw64(4 * g + r, jt * 16 + low)] = f2bf(s[jt][r]);
    asm volatile("s_waitcnt lgkmcnt(0)" ::: "memory");
    // ---- PV : O[dt] += P · V ----
    s16x8 pa0 = *(const s16x8*)&Pp[w][sw64(low, 8 * g)];
    s16x8 pa1 = *(const s16x8*)&Pp[w][sw64(low, 32 + 8 * g)];
#pragma unroll
    for (int dt = 0; dt < 4; ++dt) {
      s16x8 v0 = *(const s16x8*)&Vt[sw64(dt * 16 + low, 8 * g)];
      s16x8 v1 = *(const s16x8*)&Vt[sw64(dt * 16 + low, 32 + 8 * g)];
      O[dt] = __builtin_amdgcn_mfma_f32_16x16x32_bf16(pa0, v0, O[dt], 0, 0, 0);
      O[dt] = __builtin_amdgcn_mfma_f32_16x16x32_bf16(pa1, v1, O[dt], 0, 0, 0);
    }
  }
  // epilogue: normalize and store bf16 for the out-GEMM
  float inv[4];
#pragma unroll
  for (int r = 0; r < 4; ++r) inv[r] = 1.0f / lreg[r];
#pragma unroll
  for (int dt = 0; dt < 4; ++dt)
#pragma unroll
    for (int r = 0; r < 4; ++r)
      attn[((size_t)(b * T_ + i0 + 16 * w + 4 * g + r)) * 1024 +
           h * 64 + dt * 16 + low] = f2bf(O[dt][r] * inv[r]);
}

// ---------------------------------------------------------------------------
extern "C" void kernel_launch(void* const* d_in, const int* in_sizes, int n_in,
                              void* d_out, int out_size, void* d_ws, size_t ws_size,
                              hipStream_t stream) {
  const float* inputs = (const float*)d_in[0];
  const float* memory = (const float*)d_in[1];
  const float* w_qkv  = (const float*)d_in[2];
  const float* w_pos  = (const float*)d_in[3];
  const float* w_out  = (const float*)d_in[4];
  const float* uvar   = (const float*)d_in[5];
  const float* vvar   = (const float*)d_in[6];
  const float* gamma  = (const float*)d_in[7];
  const float* beta   = (const float*)d_in[8];
  float* out = (float*)d_out;

  // workspace layout (75,497,472 B total == previous footprint)
  float*  qkv  = (float*)d_ws;                        // 4096*3072 f  (50.33 MB)
  ushort* xnb  = (ushort*)(qkv + (size_t)4096 * 3072);// 4096*1024 bf16 (8.39 MB)
  ushort* phib = xnb + (size_t)4096 * 1024;           // 1024*1024 bf16 (2.10 MB)
  float*  Rm   = (float*)(phib + (size_t)1024 * 1024);// 1024*1024 f  (4.19 MB)
  ushort* wqb  = (ushort*)(Rm + (size_t)1024 * 1024); // 3072*1024 bf16 (6.29 MB)
  ushort* wpb  = wqb + (size_t)3072 * 1024;           // 1024*1024 bf16 (2.10 MB)
  ushort* wob  = wpb + (size_t)1024 * 1024;           // 1024*1024 bf16 (2.10 MB)
  ushort* attnb = xnb;                                // reuse xn region after QKV GEMM

  ln_concat_kernel<<<B_ * L_, 256, 0, stream>>>(inputs, memory, gamma, beta, xnb);
  phi_kernel<<<(L_ * DM_) / 256, 256, 0, stream>>>(phib);
  cast_bf16_kernel<<<(3072 * 1024 / 4 + 255) / 256, 256, 0, stream>>>(w_qkv, wqb, 3072 * 1024 / 4);
  cast_bf16_kernel<<<(1024 * 1024 / 4 + 255) / 256, 256, 0, stream>>>(w_pos, wpb, 1024 * 1024 / 4);
  cast_bf16_kernel<<<(1024 * 1024 / 4 + 255) / 256, 256, 0, stream>>>(w_out, wob, 1024 * 1024 / 4);

  gemm_nt_bf16<<<dim3(3072 / 128, 4096 / 128), 256, 0, stream>>>(xnb, wqb, qkv, 4096, 3072, 1024);
  gemm_nt_bf16<<<dim3(1024 / 128, 1024 / 128), 256, 0, stream>>>(phib, wpb, Rm, 1024, 1024, 1024);
  attn_mfma_kernel<<<dim3(B_ * H_ * 8), 256, 0, stream>>>(qkv, Rm, uvar, vvar, attnb);
  gemm_nt_bf16<<<dim3(1024 / 128, 2048 / 128), 256, 0, stream>>>(attnb, wob, out, 2048, 1024, 1024);
}

// Round 3
// 237.798 us; speedup vs baseline: 4.9781x; 1.2878x over previous
//
#include <hip/hip_runtime.h>
#include <math.h>

#define B_   4
#define T_   512
#define TAU_ 512
#define L_   1024
#define DM_  1024
#define H_   16
#define D_   64

typedef short  s16x8 __attribute__((ext_vector_type(8)));   // 8 bf16 MFMA frag
typedef ushort u16x4 __attribute__((ext_vector_type(4)));
typedef float  f32x4 __attribute__((ext_vector_type(4)));

__device__ __forceinline__ ushort f2bf(float x) {   // RNE float->bf16 bits
  uint u = __float_as_uint(x);
  u += 0x7fffu + ((u >> 16) & 1u);
  return (ushort)(u >> 16);
}
__device__ __forceinline__ float bf2f(ushort u) {
  return __uint_as_float(((uint)u) << 16);
}
// XOR-swizzle for bf16 [rows][64] LDS tiles (128B rows): permute 16B slots by row&7
__device__ __forceinline__ int sw64(int row, int col) {
  return row * 64 + (col ^ ((row & 7) << 3));
}

// ---------------------------------------------------------------------------
// LayerNorm over concat(memory, inputs) rows -> bf16 output. Block per row.
// ---------------------------------------------------------------------------
__global__ __launch_bounds__(256) void ln_concat_kernel(
    const float* __restrict__ inp, const float* __restrict__ mem,
    const float* __restrict__ gamma, const float* __restrict__ beta,
    ushort* __restrict__ xn) {
  int row = blockIdx.x;              // b*L + l
  int b = row >> 10, l = row & 1023;
  const float* src = (l < TAU_)
      ? mem + ((size_t)b * TAU_ + l) * DM_
      : inp + ((size_t)b * T_ + (l - TAU_)) * DM_;
  int t = threadIdx.x;
  float4 v = *(const float4*)(src + t * 4);
  float s  = v.x + v.y + v.z + v.w;
  float s2 = v.x * v.x + v.y * v.y + v.z * v.z + v.w * v.w;
#pragma unroll
  for (int off = 32; off > 0; off >>= 1) {
    s  += __shfl_down(s, off);
    s2 += __shfl_down(s2, off);
  }
  __shared__ float red[8];
  __shared__ float stat[2];
  int wid = t >> 6;
  if ((t & 63) == 0) { red[wid * 2] = s; red[wid * 2 + 1] = s2; }
  __syncthreads();
  if (t == 0) {
    float ts  = red[0] + red[2] + red[4] + red[6];
    float ts2 = red[1] + red[3] + red[5] + red[7];
    float mu  = ts * (1.0f / DM_);
    float var = ts2 * (1.0f / DM_) - mu * mu;
    stat[0] = mu;
    stat[1] = 1.0f / sqrtf(var + 1e-5f);
  }
  __syncthreads();
  float mu = stat[0], rstd = stat[1];
  float4 g  = *(const float4*)(gamma + t * 4);
  float4 be = *(const float4*)(beta  + t * 4);
  u16x4 o;
  o[0] = f2bf((v.x - mu) * rstd * g.x + be.x);
  o[1] = f2bf((v.y - mu) * rstd * g.y + be.y);
  o[2] = f2bf((v.z - mu) * rstd * g.z + be.z);
  o[3] = f2bf((v.w - mu) * rstd * g.w + be.w);
  *(u16x4*)(xn + (size_t)row * DM_ + t * 4) = o;
}

// ---------------------------------------------------------------------------
// phi[m][c] in bf16: m in [0,1024), pos = 1023-m; c<512 -> sin, else cos.
// ---------------------------------------------------------------------------
__global__ __launch_bounds__(256) void phi_kernel(ushort* __restrict__ phi) {
  int idx = blockIdx.x * 256 + threadIdx.x;   // 0 .. 1M-1
  int m = idx >> 10, c = idx & 1023;
  float p = (float)(1023 - m);
  int cc = (c < 512) ? c : c - 512;
  float invf = __expf(-((float)(2 * cc) * (1.0f / 1024.0f)) * 9.210340371976184f);
  float a = p * invf;
  phi[idx] = f2bf((c < 512) ? sinf(a) : cosf(a));
}

// ---------------------------------------------------------------------------
// fp32 -> bf16 cast, float4-vectorized. n4 = n/4.
// ---------------------------------------------------------------------------
__global__ __launch_bounds__(256) void cast_bf16_kernel(
    const float* __restrict__ in, ushort* __restrict__ out, int n4) {
  int i = blockIdx.x * 256 + threadIdx.x;
  if (i >= n4) return;
  float4 v = *(const float4*)(in + (size_t)i * 4);
  u16x4 o = { f2bf(v.x), f2bf(v.y), f2bf(v.z), f2bf(v.w) };
  *(u16x4*)(out + (size_t)i * 4) = o;
}

// ---------------------------------------------------------------------------
// bf16 MFMA NT GEMM: C[M,N] = A[M,K]bf16 * B[N,K]bf16^T, row-major.
// C type templated: float (final output) or ushort (bf16 intermediates).
// m97 structure: 128x128 tile, BK=32, global_load_lds staging, both-sides
// slot swizzle.
// ---------------------------------------------------------------------------
template <typename CT>
__global__ __launch_bounds__(256) void gemm_nt_bf16(
    const ushort* __restrict__ A, const ushort* __restrict__ B,
    CT* __restrict__ C, int M, int N, int K) {
  __shared__ __attribute__((aligned(16))) ushort As[128 * 32];
  __shared__ __attribute__((aligned(16))) ushort Bs[128 * 32];
  int t = threadIdx.x;
  int w = t >> 6, lane = t & 63, g = lane >> 4, low = lane & 15;
  int wr = w >> 1, wc = w & 1;               // wave 2x2 grid, 64x64 each
  int m0 = blockIdx.y * 128, n0 = blockIdx.x * 128;
  f32x4 acc[4][4] = {};

  for (int kt = 0; kt < K; kt += 32) {
    __syncthreads();                         // prev-iter LDS reads done
#pragma unroll
    for (int q = 0; q < 2; ++q) {
      int f = t + q * 256;                   // chunk 0..511 (16B each)
      int row = f >> 2;
      int gslot = (f & 3) ^ ((row >> 1) & 3);
      const ushort* ga = A + (size_t)(m0 + row) * K + kt + gslot * 8;
      const ushort* gb = B + (size_t)(n0 + row) * K + kt + gslot * 8;
      __builtin_amdgcn_global_load_lds(
          (const __attribute__((address_space(1))) void*)ga,
          (__attribute__((address_space(3))) void*)&As[(q * 256 + w * 64) * 8],
          16, 0, 0);
      __builtin_amdgcn_global_load_lds(
          (const __attribute__((address_space(1))) void*)gb,
          (__attribute__((address_space(3))) void*)&Bs[(q * 256 + w * 64) * 8],
          16, 0, 0);
    }
    __syncthreads();                         // vmcnt(0) drain: tiles ready

    s16x8 af[4], bfr[4];
#pragma unroll
    for (int mi = 0; mi < 4; ++mi) {
      int row = wr * 64 + mi * 16 + low;
      af[mi] = *(const s16x8*)&As[row * 32 + ((g ^ ((row >> 1) & 3)) * 8)];
    }
#pragma unroll
    for (int ni = 0; ni < 4; ++ni) {
      int col = wc * 64 + ni * 16 + low;
      bfr[ni] = *(const s16x8*)&Bs[col * 32 + ((g ^ ((col >> 1) & 3)) * 8)];
    }
#pragma unroll
    for (int mi = 0; mi < 4; ++mi)
#pragma unroll
      for (int ni = 0; ni < 4; ++ni)
        acc[mi][ni] = __builtin_amdgcn_mfma_f32_16x16x32_bf16(
            af[mi], bfr[ni], acc[mi][ni], 0, 0, 0);
  }
#pragma unroll
  for (int mi = 0; mi < 4; ++mi)
#pragma unroll
    for (int ni = 0; ni < 4; ++ni)
#pragma unroll
      for (int r = 0; r < 4; ++r) {
        int m = m0 + wr * 64 + mi * 16 + 4 * g + r;
        int n = n0 + wc * 64 + ni * 16 + low;
        if constexpr (sizeof(CT) == 2)
          C[(size_t)m * N + n] = f2bf(acc[mi][ni][r]);
        else
          C[(size_t)m * N + n] = acc[mi][ni][r];
      }
}

// ---------------------------------------------------------------------------
// Transpose the V third of qkv (bf16) into vtg[(b*16+h)*64 + d][L].
// Block = (b, h, 64-row l-tile). Conflict-free via [64][65] ushort LDS.
// ---------------------------------------------------------------------------
__global__ __launch_bounds__(256) void vtrans_kernel(
    const ushort* __restrict__ qkv, ushort* __restrict__ vtg) {
  __shared__ ushort vs[64 * 65];
  int bid = blockIdx.x;
  int lt = bid & 15;
  int h  = (bid >> 4) & 15;
  int b  = bid >> 8;
  int l0 = lt * 64;
  int t = threadIdx.x;
#pragma unroll
  for (int q = 0; q < 2; ++q) {
    int c = t + q * 256;
    int row = c >> 3, sl = c & 7;
    s16x8 v = *(const s16x8*)(qkv +
        (size_t)(b * L_ + l0 + row) * 3072 + 2048 + h * 64 + sl * 8);
#pragma unroll
    for (int e = 0; e < 8; ++e) vs[row * 65 + sl * 8 + e] = (ushort)v[e];
  }
  __syncthreads();
#pragma unroll
  for (int q = 0; q < 2; ++q) {
    int c = t + q * 256;
    int d = c >> 3, sl = c & 7;
    s16x8 o;
#pragma unroll
    for (int e = 0; e < 8; ++e) o[e] = (short)vs[(sl * 8 + e) * 65 + d];
    *(s16x8*)(vtg + (size_t)((b * 16 + h) * 64 + d) * 1024 + l0 + sl * 8) = o;
  }
}

// ---------------------------------------------------------------------------
// MFMA bf16 flash attention with rel-shift. All operands bf16 in global.
// Double-buffered global_load_lds staging (T3-minimum 2-phase), shfl-based
// rel-shift (no Ps spill), one barrier per tile. LDS 72KB -> 2 blocks/CU.
// ---------------------------------------------------------------------------
__global__ __launch_bounds__(256) void attn_mfma_kernel(
    const ushort* __restrict__ qkv, const ushort* __restrict__ Rm,
    const ushort* __restrict__ vtg,
    const float* __restrict__ uvar, const float* __restrict__ vvar,
    ushort* __restrict__ attn) {
  __shared__ __attribute__((aligned(16))) ushort Ks[2][64 * 64];
  __shared__ __attribute__((aligned(16))) ushort Vt[2][64 * 64];
  __shared__ __attribute__((aligned(16))) ushort Rs[2][128 * 64];
  __shared__ __attribute__((aligned(16))) ushort Pp[4][16 * 64];

  int t   = threadIdx.x;
  int w   = t >> 6;          // wave 0..3
  int lw  = t & 63;
  int g   = lw >> 4;         // k-group 0..3
  int low = lw & 15;

  int bid = blockIdx.x;
  int bi  = bid & 7;
  int h   = (bid >> 3) & 15;
  int b   = bid >> 7;
  int i0  = bi * 64;
  int lb_w = 48 - 16 * w;    // wave's P m-window base within Rs

  // async stage of one j-tile into buffer buf (K, V^T, R) — all via
  // global_load_lds w=16; LDS linear dest, swizzle applied on the SOURCE.
  auto stage = [&](int buf, int tl) {
    int j0s = tl * 64;
#pragma unroll
    for (int q = 0; q < 2; ++q) {
      int c = t + q * 256;                  // 16B chunk id 0..511
      int row = c >> 3;
      int sl = (c & 7) ^ (row & 7);         // inverse slot swizzle on source
      const ushort* srck = qkv + (size_t)(b * L_ + j0s + row) * 3072 +
                           1024 + h * 64 + sl * 8;
      __builtin_amdgcn_global_load_lds(
          (const __attribute__((address_space(1))) void*)srck,
          (__attribute__((address_space(3))) void*)&Ks[buf][(q * 256 + w * 64) * 8],
          16, 0, 0);
      const ushort* srcv = vtg + (size_t)((b * 16 + h) * 64 + row) * 1024 +
                           j0s + sl * 8;
      __builtin_amdgcn_global_load_lds(
          (const __attribute__((address_space(1))) void*)srcv,
          (__attribute__((address_space(3))) void*)&Vt[buf][(q * 256 + w * 64) * 8],
          16, 0, 0);
    }
    int mb = j0s + 448 - i0;
#pragma unroll
    for (int q = 0; q < 4; ++q) {
      int c = t + q * 256;                  // chunk 0..1023
      int row = c >> 3;                     // R row 0..127
      int m = mb + row; m = (m > 1023) ? 1023 : m;
      int sl = (c & 7) ^ (row & 7);
      const ushort* srcr = Rm + (size_t)m * 1024 + h * 64 + sl * 8;
      __builtin_amdgcn_global_load_lds(
          (const __attribute__((address_space(1))) void*)srcr,
          (__attribute__((address_space(3))) void*)&Rs[buf][(q * 256 + w * 64) * 8],
          16, 0, 0);
    }
  };

  // Q fragments (bf16 source + fp32 u/v), loaded once
  int iq = i0 + 16 * w + low;
  s16x8 qu[2], qv[2];
  {
    const ushort* qrow = qkv + (size_t)(b * L_ + TAU_ + iq) * 3072 + h * 64;
    const float* ur = uvar + h * 64;
    const float* vr = vvar + h * 64;
#pragma unroll
    for (int kc = 0; kc < 2; ++kc) {
      int dbase = kc * 32 + 8 * g;
#pragma unroll
      for (int e = 0; e < 8; ++e) {
        float q = bf2f(qrow[dbase + e]);
        qu[kc][e] = (short)f2bf(q + ur[dbase + e]);
        qv[kc][e] = (short)f2bf(q + vr[dbase + e]);
      }
    }
  }

  f32x4 O[4] = {};
  float mreg[4] = {-INFINITY, -INFINITY, -INFINITY, -INFINITY};
  float lreg[4] = {0.f, 0.f, 0.f, 0.f};

  int ntiles = 9 + bi;       // covers j <= TAU + i0 + 63 exactly
  stage(0, 0);
  __syncthreads();           // drains vmcnt: tile 0 ready
  int cur = 0;
  for (int tile = 0; tile < ntiles; ++tile) {
    int j0 = tile * 64;
    if (tile + 1 < ntiles) stage(cur ^ 1, tile + 1);   // prefetch next

    // ---- QK^T ----
    f32x4 s[4] = {};
#pragma unroll
    for (int jt = 0; jt < 4; ++jt) {
#pragma unroll
      for (int kc = 0; kc < 2; ++kc) {
        s16x8 kb = *(const s16x8*)&Ks[cur][sw64(jt * 16 + low, kc * 32 + 8 * g)];
        s[jt] = __builtin_amdgcn_mfma_f32_16x16x32_bf16(qu[kc], kb, s[jt], 0, 0, 0);
      }
    }
    // ---- P = (q+v)·R over the wave's 80-col m-window ----
    f32x4 p[5] = {};
#pragma unroll
    for (int mt = 0; mt < 5; ++mt) {
#pragma unroll
      for (int kc = 0; kc < 2; ++kc) {
        s16x8 rb = *(const s16x8*)&Rs[cur][sw64(lb_w + mt * 16 + low, kc * 32 + 8 * g)];
        p[mt] = __builtin_amdgcn_mfma_f32_16x16x32_bf16(qv[kc], rb, p[mt], 0, 0, 0);
      }
    }
    // ---- rel-shift via bpermute + mask + online softmax ----
#pragma unroll
    for (int r = 0; r < 4; ++r) {
      int iL = 4 * g + r;
      int src = g * 16 + ((low + 15 - iL) & 15);   // D-layout: col=lane&15
      float sh0 = __shfl(p[0][r], src);
      float sh1 = __shfl(p[1][r], src);
      float sh2 = __shfl(p[2][r], src);
      float sh3 = __shfl(p[3][r], src);
      float sh4 = __shfl(p[4][r], src);
      bool lo = (low <= iL);
      float po0 = lo ? sh0 : sh1;
      float po1 = lo ? sh1 : sh2;
      float po2 = lo ? sh2 : sh3;
      float po3 = lo ? sh3 : sh4;
      int lim = TAU_ + i0 + 16 * w + iL;
      s[0][r] = (j0 + 0 * 16 + low <= lim) ? (s[0][r] + po0) * 0.125f : -1e30f;
      s[1][r] = (j0 + 1 * 16 + low <= lim) ? (s[1][r] + po1) * 0.125f : -1e30f;
      s[2][r] = (j0 + 2 * 16 + low <= lim) ? (s[2][r] + po2) * 0.125f : -1e30f;
      s[3][r] = (j0 + 3 * 16 + low <= lim) ? (s[3][r] + po3) * 0.125f : -1e30f;
    }
#pragma unroll
    for (int r = 0; r < 4; ++r) {
      float mx = fmaxf(fmaxf(s[0][r], s[1][r]), fmaxf(s[2][r], s[3][r]));
      mx = fmaxf(mx, __shfl_xor(mx, 1));
      mx = fmaxf(mx, __shfl_xor(mx, 2));
      mx = fmaxf(mx, __shfl_xor(mx, 4));
      mx = fmaxf(mx, __shfl_xor(mx, 8));
      float mn = fmaxf(mreg[r], mx);
      float alpha = __expf(mreg[r] - mn);
      mreg[r] = mn;
      float sum = 0.f;
#pragma unroll
      for (int jt = 0; jt < 4; ++jt) {
        float pe = __expf(s[jt][r] - mn);
        s[jt][r] = pe;
        sum += pe;
      }
      sum += __shfl_xor(sum, 1);
      sum += __shfl_xor(sum, 2);
      sum += __shfl_xor(sum, 4);
      sum += __shfl_xor(sum, 8);
      lreg[r] = lreg[r] * alpha + sum;
      O[0][r] *= alpha; O[1][r] *= alpha; O[2][r] *= alpha; O[3][r] *= alpha;
    }
    // ---- P -> bf16 LDS (C-layout -> A-layout transpose) ----
#pragma unroll
    for (int jt = 0; jt < 4; ++jt)
#pragma unroll
      for (int r = 0; r < 4; ++r)
        Pp[w][sw64(4 * g + r, jt * 16 + low)] = f2bf(s[jt][r]);
    asm volatile("s_waitcnt lgkmcnt(0)" ::: "memory");
    s16x8 pa0 = *(const s16x8*)&Pp[w][sw64(low, 8 * g)];
    s16x8 pa1 = *(const s16x8*)&Pp[w][sw64(low, 32 + 8 * g)];
    // ---- PV ----
#pragma unroll
    for (int dt = 0; dt < 4; ++dt) {
      s16x8 v0 = *(const s16x8*)&Vt[cur][sw64(dt * 16 + low, 8 * g)];
      s16x8 v1 = *(const s16x8*)&Vt[cur][sw64(dt * 16 + low, 32 + 8 * g)];
      O[dt] = __builtin_amdgcn_mfma_f32_16x16x32_bf16(pa0, v0, O[dt], 0, 0, 0);
      O[dt] = __builtin_amdgcn_mfma_f32_16x16x32_bf16(pa1, v1, O[dt], 0, 0, 0);
    }
    __syncthreads();         // all LDS reads done + next-tile DMA landed
    cur ^= 1;
  }
  // epilogue: normalize, store bf16 for the out-GEMM
  float inv[4];
#pragma unroll
  for (int r = 0; r < 4; ++r) inv[r] = 1.0f / lreg[r];
#pragma unroll
  for (int dt = 0; dt < 4; ++dt)
#pragma unroll
    for (int r = 0; r < 4; ++r)
      attn[((size_t)(b * T_ + i0 + 16 * w + 4 * g + r)) * 1024 +
           h * 64 + dt * 16 + low] = f2bf(O[dt][r] * inv[r]);
}

// ---------------------------------------------------------------------------
extern "C" void kernel_launch(void* const* d_in, const int* in_sizes, int n_in,
                              void* d_out, int out_size, void* d_ws, size_t ws_size,
                              hipStream_t stream) {
  const float* inputs = (const float*)d_in[0];
  const float* memory = (const float*)d_in[1];
  const float* w_qkv  = (const float*)d_in[2];
  const float* w_pos  = (const float*)d_in[3];
  const float* w_out  = (const float*)d_in[4];
  const float* uvar   = (const float*)d_in[5];
  const float* vvar   = (const float*)d_in[6];
  const float* gamma  = (const float*)d_in[7];
  const float* beta   = (const float*)d_in[8];
  float* out = (float*)d_out;

  // workspace layout, all bf16 (56.6 MB < previous 75.5 MB footprint)
  ushort* qkvB = (ushort*)d_ws;                       // 4096*3072
  ushort* xnb  = qkvB + (size_t)4096 * 3072;          // 4096*1024
  ushort* phib = xnb  + (size_t)4096 * 1024;          // 1024*1024
  ushort* RmB  = phib + (size_t)1024 * 1024;          // 1024*1024
  ushort* wqb  = RmB  + (size_t)1024 * 1024;          // 3072*1024
  ushort* wpb  = wqb  + (size_t)3072 * 1024;          // 1024*1024
  ushort* wob  = wpb  + (size_t)1024 * 1024;          // 1024*1024
  ushort* vtg  = wob  + (size_t)1024 * 1024;          // 4096*1024 (V^T)
  ushort* attnb = xnb;                                // reuse after QKV GEMM

  ln_concat_kernel<<<B_ * L_, 256, 0, stream>>>(inputs, memory, gamma, beta, xnb);
  phi_kernel<<<(L_ * DM_) / 256, 256, 0, stream>>>(phib);
  cast_bf16_kernel<<<(3072 * 1024 / 4 + 255) / 256, 256, 0, stream>>>(w_qkv, wqb, 3072 * 1024 / 4);
  cast_bf16_kernel<<<(1024 * 1024 / 4 + 255) / 256, 256, 0, stream>>>(w_pos, wpb, 1024 * 1024 / 4);
  cast_bf16_kernel<<<(1024 * 1024 / 4 + 255) / 256, 256, 0, stream>>>(w_out, wob, 1024 * 1024 / 4);

  gemm_nt_bf16<ushort><<<dim3(3072 / 128, 4096 / 128), 256, 0, stream>>>(
      xnb, wqb, qkvB, 4096, 3072, 1024);
  gemm_nt_bf16<ushort><<<dim3(1024 / 128, 1024 / 128), 256, 0, stream>>>(
      phib, wpb, RmB, 1024, 1024, 1024);
  vtrans_kernel<<<B_ * H_ * 16, 256, 0, stream>>>(qkvB, vtg);
  attn_mfma_kernel<<<dim3(B_ * H_ * 8), 256, 0, stream>>>(qkvB, RmB, vtg, uvar, vvar, attnb);
  gemm_nt_bf16<float><<<dim3(1024 / 128, 2048 / 128), 256, 0, stream>>>(
      attnb, wob, out, 2048, 1024, 1024);
}

// Round 4
// 229.372 us; speedup vs baseline: 5.1610x; 1.0367x over previous
//
#include <hip/hip_runtime.h>
#include <math.h>

#define B_   4
#define T_   512
#define TAU_ 512
#define L_   1024
#define DM_  1024
#define H_   16
#define D_   64

typedef short  s16x8 __attribute__((ext_vector_type(8)));   // 8 bf16 MFMA frag
typedef ushort u16x4 __attribute__((ext_vector_type(4)));
typedef float  f32x4 __attribute__((ext_vector_type(4)));

#define SC_LOG2 0.18033688011f   // 0.125 * log2(e): softmax runs in exp2 domain

__device__ __forceinline__ ushort f2bf(float x) {   // RNE float->bf16 bits
  uint u = __float_as_uint(x);
  u += 0x7fffu + ((u >> 16) & 1u);
  return (ushort)(u >> 16);
}
__device__ __forceinline__ float bf2f(ushort u) {
  return __uint_as_float(((uint)u) << 16);
}
// XOR-swizzle for bf16 [rows][64] LDS tiles (128B rows): permute 16B slots by row&7
__device__ __forceinline__ int sw64(int row, int col) {
  return row * 64 + (col ^ ((row & 7) << 3));
}

// ---------------------------------------------------------------------------
// Fused preprocessing: [0,4096) LayerNorm rows -> bf16 xn;
// [4096,8192) phi table; [8192,13312) weight fp32->bf16 casts.
// All branches independent; branch is block-uniform.
// ---------------------------------------------------------------------------
__global__ __launch_bounds__(256) void prep_kernel(
    const float* __restrict__ inp, const float* __restrict__ mem,
    const float* __restrict__ gamma, const float* __restrict__ beta,
    ushort* __restrict__ xn, ushort* __restrict__ phi,
    const float* __restrict__ wq, ushort* __restrict__ wqb,
    const float* __restrict__ wp, ushort* __restrict__ wpb,
    const float* __restrict__ wo, ushort* __restrict__ wob) {
  int blk = blockIdx.x;
  int t = threadIdx.x;
  if (blk < 4096) {                    // ---- LayerNorm ----
    int row = blk;                     // b*L + l
    int b = row >> 10, l = row & 1023;
    const float* src = (l < TAU_)
        ? mem + ((size_t)b * TAU_ + l) * DM_
        : inp + ((size_t)b * T_ + (l - TAU_)) * DM_;
    float4 v = *(const float4*)(src + t * 4);
    float s  = v.x + v.y + v.z + v.w;
    float s2 = v.x * v.x + v.y * v.y + v.z * v.z + v.w * v.w;
#pragma unroll
    for (int off = 32; off > 0; off >>= 1) {
      s  += __shfl_down(s, off);
      s2 += __shfl_down(s2, off);
    }
    __shared__ float red[8];
    __shared__ float stat[2];
    int wid = t >> 6;
    if ((t & 63) == 0) { red[wid * 2] = s; red[wid * 2 + 1] = s2; }
    __syncthreads();
    if (t == 0) {
      float ts  = red[0] + red[2] + red[4] + red[6];
      float ts2 = red[1] + red[3] + red[5] + red[7];
      float mu  = ts * (1.0f / DM_);
      float var = ts2 * (1.0f / DM_) - mu * mu;
      stat[0] = mu;
      stat[1] = 1.0f / sqrtf(var + 1e-5f);
    }
    __syncthreads();
    float mu = stat[0], rstd = stat[1];
    float4 g  = *(const float4*)(gamma + t * 4);
    float4 be = *(const float4*)(beta  + t * 4);
    u16x4 o;
    o[0] = f2bf((v.x - mu) * rstd * g.x + be.x);
    o[1] = f2bf((v.y - mu) * rstd * g.y + be.y);
    o[2] = f2bf((v.z - mu) * rstd * g.z + be.z);
    o[3] = f2bf((v.w - mu) * rstd * g.w + be.w);
    *(u16x4*)(xn + (size_t)row * DM_ + t * 4) = o;
  } else if (blk < 8192) {             // ---- phi ----
    int idx = (blk - 4096) * 256 + t;  // 0 .. 1M-1
    int m = idx >> 10, c = idx & 1023;
    float p = (float)(1023 - m);
    int cc = (c < 512) ? c : c - 512;
    float invf = __expf(-((float)(2 * cc) * (1.0f / 1024.0f)) * 9.210340371976184f);
    float a = p * invf;
    phi[idx] = f2bf((c < 512) ? sinf(a) : cosf(a));
  } else {                             // ---- weight casts ----
    int i = (blk - 8192) * 256 + t;    // float4-group index, < 1310720
    const float* src; ushort* dst; int off;
    if (i < 786432)       { src = wq; dst = wqb; off = i; }
    else if (i < 1048576) { src = wp; dst = wpb; off = i - 786432; }
    else                  { src = wo; dst = wob; off = i - 1048576; }
    float4 v = *(const float4*)(src + (size_t)off * 4);
    u16x4 o = { f2bf(v.x), f2bf(v.y), f2bf(v.z), f2bf(v.w) };
    *(u16x4*)(dst + (size_t)off * 4) = o;
  }
}

// ---------------------------------------------------------------------------
// bf16 MFMA NT GEMM body: C[M,N] = A[M,K]bf16 * B[N,K]bf16^T, row-major.
// m97 structure: 128x128 tile, BK=32, global_load_lds staging, both-sides
// slot swizzle. Called from block-range dispatcher kernels.
// ---------------------------------------------------------------------------
template <typename CT>
__device__ __forceinline__ void gemm_nt_body(
    const ushort* __restrict__ A, const ushort* __restrict__ B,
    CT* __restrict__ C, int M, int N, int K, int bx, int by) {
  __shared__ __attribute__((aligned(16))) ushort As[128 * 32];
  __shared__ __attribute__((aligned(16))) ushort Bs[128 * 32];
  int t = threadIdx.x;
  int w = t >> 6, lane = t & 63, g = lane >> 4, low = lane & 15;
  int wr = w >> 1, wc = w & 1;               // wave 2x2 grid, 64x64 each
  int m0 = by * 128, n0 = bx * 128;
  f32x4 acc[4][4] = {};

  for (int kt = 0; kt < K; kt += 32) {
    __syncthreads();                         // prev-iter LDS reads done
#pragma unroll
    for (int q = 0; q < 2; ++q) {
      int f = t + q * 256;                   // chunk 0..511 (16B each)
      int row = f >> 2;
      int gslot = (f & 3) ^ ((row >> 1) & 3);
      const ushort* ga = A + (size_t)(m0 + row) * K + kt + gslot * 8;
      const ushort* gb = B + (size_t)(n0 + row) * K + kt + gslot * 8;
      __builtin_amdgcn_global_load_lds(
          (const __attribute__((address_space(1))) void*)ga,
          (__attribute__((address_space(3))) void*)&As[(q * 256 + w * 64) * 8],
          16, 0, 0);
      __builtin_amdgcn_global_load_lds(
          (const __attribute__((address_space(1))) void*)gb,
          (__attribute__((address_space(3))) void*)&Bs[(q * 256 + w * 64) * 8],
          16, 0, 0);
    }
    __syncthreads();                         // vmcnt(0) drain: tiles ready

    s16x8 af[4], bfr[4];
#pragma unroll
    for (int mi = 0; mi < 4; ++mi) {
      int row = wr * 64 + mi * 16 + low;
      af[mi] = *(const s16x8*)&As[row * 32 + ((g ^ ((row >> 1) & 3)) * 8)];
    }
#pragma unroll
    for (int ni = 0; ni < 4; ++ni) {
      int col = wc * 64 + ni * 16 + low;
      bfr[ni] = *(const s16x8*)&Bs[col * 32 + ((g ^ ((col >> 1) & 3)) * 8)];
    }
    __builtin_amdgcn_s_setprio(1);
#pragma unroll
    for (int mi = 0; mi < 4; ++mi)
#pragma unroll
      for (int ni = 0; ni < 4; ++ni)
        acc[mi][ni] = __builtin_amdgcn_mfma_f32_16x16x32_bf16(
            af[mi], bfr[ni], acc[mi][ni], 0, 0, 0);
    __builtin_amdgcn_s_setprio(0);
  }
#pragma unroll
  for (int mi = 0; mi < 4; ++mi)
#pragma unroll
    for (int ni = 0; ni < 4; ++ni)
#pragma unroll
      for (int r = 0; r < 4; ++r) {
        int m = m0 + wr * 64 + mi * 16 + 4 * g + r;
        int n = n0 + wc * 64 + ni * 16 + low;
        if constexpr (sizeof(CT) == 2)
          C[(size_t)m * N + n] = f2bf(acc[mi][ni][r]);
        else
          C[(size_t)m * N + n] = acc[mi][ni][r];
      }
}

// QKV GEMM (768 blocks) + R GEMM (64 blocks) in one dispatch.
__global__ __launch_bounds__(256) void qkv_r_gemm(
    const ushort* __restrict__ xnb, const ushort* __restrict__ wqb,
    ushort* __restrict__ qkvB,
    const ushort* __restrict__ phib, const ushort* __restrict__ wpb,
    ushort* __restrict__ RmB) {
  int id = blockIdx.x;
  if (id < 768)
    gemm_nt_body<ushort>(xnb, wqb, qkvB, 4096, 3072, 1024, id % 24, id / 24);
  else {
    id -= 768;
    gemm_nt_body<ushort>(phib, wpb, RmB, 1024, 1024, 1024, id % 8, id / 8);
  }
}

__global__ __launch_bounds__(256) void out_gemm(
    const ushort* __restrict__ attnb, const ushort* __restrict__ wob,
    float* __restrict__ out) {
  gemm_nt_body<float>(attnb, wob, out, 2048, 1024, 1024,
                      blockIdx.x % 8, blockIdx.x / 8);
}

// ---------------------------------------------------------------------------
// Transpose the V third of qkv (bf16) into vtg[(b*16+h)*64 + d][L].
// ---------------------------------------------------------------------------
__global__ __launch_bounds__(256) void vtrans_kernel(
    const ushort* __restrict__ qkv, ushort* __restrict__ vtg) {
  __shared__ ushort vs[64 * 65];
  int bid = blockIdx.x;
  int lt = bid & 15;
  int h  = (bid >> 4) & 15;
  int b  = bid >> 8;
  int l0 = lt * 64;
  int t = threadIdx.x;
#pragma unroll
  for (int q = 0; q < 2; ++q) {
    int c = t + q * 256;
    int row = c >> 3, sl = c & 7;
    s16x8 v = *(const s16x8*)(qkv +
        (size_t)(b * L_ + l0 + row) * 3072 + 2048 + h * 64 + sl * 8);
#pragma unroll
    for (int e = 0; e < 8; ++e) vs[row * 65 + sl * 8 + e] = (ushort)v[e];
  }
  __syncthreads();
#pragma unroll
  for (int q = 0; q < 2; ++q) {
    int c = t + q * 256;
    int d = c >> 3, sl = c & 7;
    s16x8 o;
#pragma unroll
    for (int e = 0; e < 8; ++e) o[e] = (short)vs[(sl * 8 + e) * 65 + d];
    *(s16x8*)(vtg + (size_t)((b * 16 + h) * 64 + d) * 1024 + l0 + sl * 8) = o;
  }
}

// ---------------------------------------------------------------------------
// MFMA bf16 flash attention with rel-shift. All operands bf16 in global.
// Double-buffered global_load_lds staging, shfl rel-shift, exp2-domain
// online softmax, wave-uniform mask skip, setprio around MFMA clusters.
// Load balance: bi complemented on odd h so co-resident blocks (bid, bid+8)
// sum to a constant 25 tile-iterations.
// ---------------------------------------------------------------------------
__global__ __launch_bounds__(256) void attn_mfma_kernel(
    const ushort* __restrict__ qkv, const ushort* __restrict__ Rm,
    const ushort* __restrict__ vtg,
    const float* __restrict__ uvar, const float* __restrict__ vvar,
    ushort* __restrict__ attn) {
  __shared__ __attribute__((aligned(16))) ushort Ks[2][64 * 64];
  __shared__ __attribute__((aligned(16))) ushort Vt[2][64 * 64];
  __shared__ __attribute__((aligned(16))) ushort Rs[2][128 * 64];
  __shared__ __attribute__((aligned(16))) ushort Pp[4][16 * 64];

  int t   = threadIdx.x;
  int w   = t >> 6;          // wave 0..3
  int lw  = t & 63;
  int g   = lw >> 4;         // k-group 0..3
  int low = lw & 15;

  int bid = blockIdx.x;
  int bi_r = bid & 7;
  int h   = (bid >> 3) & 15;
  int b   = bid >> 7;
  int bi  = (h & 1) ? (7 - bi_r) : bi_r;   // load-balance complement
  int i0  = bi * 64;
  int lb_w = 48 - 16 * w;    // wave's P m-window base within Rs

  auto stage = [&](int buf, int tl) {
    int j0s = tl * 64;
#pragma unroll
    for (int q = 0; q < 2; ++q) {
      int c = t + q * 256;                  // 16B chunk id 0..511
      int row = c >> 3;
      int sl = (c & 7) ^ (row & 7);         // inverse slot swizzle on source
      const ushort* srck = qkv + (size_t)(b * L_ + j0s + row) * 3072 +
                           1024 + h * 64 + sl * 8;
      __builtin_amdgcn_global_load_lds(
          (const __attribute__((address_space(1))) void*)srck,
          (__attribute__((address_space(3))) void*)&Ks[buf][(q * 256 + w * 64) * 8],
          16, 0, 0);
      const ushort* srcv = vtg + (size_t)((b * 16 + h) * 64 + row) * 1024 +
                           j0s + sl * 8;
      __builtin_amdgcn_global_load_lds(
          (const __attribute__((address_space(1))) void*)srcv,
          (__attribute__((address_space(3))) void*)&Vt[buf][(q * 256 + w * 64) * 8],
          16, 0, 0);
    }
    int mb = j0s + 448 - i0;
#pragma unroll
    for (int q = 0; q < 4; ++q) {
      int c = t + q * 256;                  // chunk 0..1023
      int row = c >> 3;                     // R row 0..127
      int m = mb + row; m = (m > 1023) ? 1023 : m;
      int sl = (c & 7) ^ (row & 7);
      const ushort* srcr = Rm + (size_t)m * 1024 + h * 64 + sl * 8;
      __builtin_amdgcn_global_load_lds(
          (const __attribute__((address_space(1))) void*)srcr,
          (__attribute__((address_space(3))) void*)&Rs[buf][(q * 256 + w * 64) * 8],
          16, 0, 0);
    }
  };

  // Q fragments (bf16 source + fp32 u/v), loaded once
  int iq = i0 + 16 * w + low;
  s16x8 qu[2], qv[2];
  {
    const ushort* qrow = qkv + (size_t)(b * L_ + TAU_ + iq) * 3072 + h * 64;
    const float* ur = uvar + h * 64;
    const float* vr = vvar + h * 64;
#pragma unroll
    for (int kc = 0; kc < 2; ++kc) {
      int dbase = kc * 32 + 8 * g;
#pragma unroll
      for (int e = 0; e < 8; ++e) {
        float q = bf2f(qrow[dbase + e]);
        qu[kc][e] = (short)f2bf(q + ur[dbase + e]);
        qv[kc][e] = (short)f2bf(q + vr[dbase + e]);
      }
    }
  }

  f32x4 O[4] = {};
  float mreg[4] = {-INFINITY, -INFINITY, -INFINITY, -INFINITY};
  float lreg[4] = {0.f, 0.f, 0.f, 0.f};

  int ntiles = 9 + bi;       // covers j <= TAU + i0 + 63 exactly
  stage(0, 0);
  __syncthreads();           // drains vmcnt: tile 0 ready
  int cur = 0;
  for (int tile = 0; tile < ntiles; ++tile) {
    int j0 = tile * 64;
    if (tile + 1 < ntiles) stage(cur ^ 1, tile + 1);   // prefetch next

    // ---- QK^T + P=(q+v)·R (MFMA cluster, prio-boosted) ----
    f32x4 s[4] = {};
    f32x4 p[5] = {};
    __builtin_amdgcn_s_setprio(1);
#pragma unroll
    for (int jt = 0; jt < 4; ++jt) {
#pragma unroll
      for (int kc = 0; kc < 2; ++kc) {
        s16x8 kb = *(const s16x8*)&Ks[cur][sw64(jt * 16 + low, kc * 32 + 8 * g)];
        s[jt] = __builtin_amdgcn_mfma_f32_16x16x32_bf16(qu[kc], kb, s[jt], 0, 0, 0);
      }
    }
#pragma unroll
    for (int mt = 0; mt < 5; ++mt) {
#pragma unroll
      for (int kc = 0; kc < 2; ++kc) {
        s16x8 rb = *(const s16x8*)&Rs[cur][sw64(lb_w + mt * 16 + low, kc * 32 + 8 * g)];
        p[mt] = __builtin_amdgcn_mfma_f32_16x16x32_bf16(qv[kc], rb, p[mt], 0, 0, 0);
      }
    }
    __builtin_amdgcn_s_setprio(0);

    // ---- rel-shift via shfl + scale(+mask) in exp2 domain ----
    bool fullvalid = (j0 + 63 <= TAU_ + i0 + 16 * w);   // wave-uniform
#pragma unroll
    for (int r = 0; r < 4; ++r) {
      int iL = 4 * g + r;
      int src = g * 16 + ((low + 15 - iL) & 15);   // D-layout: col=lane&15
      float sh0 = __shfl(p[0][r], src);
      float sh1 = __shfl(p[1][r], src);
      float sh2 = __shfl(p[2][r], src);
      float sh3 = __shfl(p[3][r], src);
      float sh4 = __shfl(p[4][r], src);
      bool lo = (low <= iL);
      float po0 = lo ? sh0 : sh1;
      float po1 = lo ? sh1 : sh2;
      float po2 = lo ? sh2 : sh3;
      float po3 = lo ? sh3 : sh4;
      if (fullvalid) {
        s[0][r] = (s[0][r] + po0) * SC_LOG2;
        s[1][r] = (s[1][r] + po1) * SC_LOG2;
        s[2][r] = (s[2][r] + po2) * SC_LOG2;
        s[3][r] = (s[3][r] + po3) * SC_LOG2;
      } else {
        int lim = TAU_ + i0 + 16 * w + iL;
        s[0][r] = (j0 +  0 + low <= lim) ? (s[0][r] + po0) * SC_LOG2 : -1e30f;
        s[1][r] = (j0 + 16 + low <= lim) ? (s[1][r] + po1) * SC_LOG2 : -1e30f;
        s[2][r] = (j0 + 32 + low <= lim) ? (s[2][r] + po2) * SC_LOG2 : -1e30f;
        s[3][r] = (j0 + 48 + low <= lim) ? (s[3][r] + po3) * SC_LOG2 : -1e30f;
      }
    }
    // ---- online softmax (exp2 domain) ----
#pragma unroll
    for (int r = 0; r < 4; ++r) {
      float mx = fmaxf(fmaxf(s[0][r], s[1][r]), fmaxf(s[2][r], s[3][r]));
      mx = fmaxf(mx, __shfl_xor(mx, 1));
      mx = fmaxf(mx, __shfl_xor(mx, 2));
      mx = fmaxf(mx, __shfl_xor(mx, 4));
      mx = fmaxf(mx, __shfl_xor(mx, 8));
      float mn = fmaxf(mreg[r], mx);
      float alpha = exp2f(mreg[r] - mn);
      mreg[r] = mn;
      float sum = 0.f;
#pragma unroll
      for (int jt = 0; jt < 4; ++jt) {
        float pe = exp2f(s[jt][r] - mn);
        s[jt][r] = pe;
        sum += pe;
      }
      sum += __shfl_xor(sum, 1);
      sum += __shfl_xor(sum, 2);
      sum += __shfl_xor(sum, 4);
      sum += __shfl_xor(sum, 8);
      lreg[r] = lreg[r] * alpha + sum;
      O[0][r] *= alpha; O[1][r] *= alpha; O[2][r] *= alpha; O[3][r] *= alpha;
    }
    // ---- P -> bf16 LDS (C-layout -> A-layout transpose) ----
#pragma unroll
    for (int jt = 0; jt < 4; ++jt)
#pragma unroll
      for (int r = 0; r < 4; ++r)
        Pp[w][sw64(4 * g + r, jt * 16 + low)] = f2bf(s[jt][r]);
    asm volatile("s_waitcnt lgkmcnt(0)" ::: "memory");
    s16x8 pa0 = *(const s16x8*)&Pp[w][sw64(low, 8 * g)];
    s16x8 pa1 = *(const s16x8*)&Pp[w][sw64(low, 32 + 8 * g)];
    // ---- PV ----
    __builtin_amdgcn_s_setprio(1);
#pragma unroll
    for (int dt = 0; dt < 4; ++dt) {
      s16x8 v0 = *(const s16x8*)&Vt[cur][sw64(dt * 16 + low, 8 * g)];
      s16x8 v1 = *(const s16x8*)&Vt[cur][sw64(dt * 16 + low, 32 + 8 * g)];
      O[dt] = __builtin_amdgcn_mfma_f32_16x16x32_bf16(pa0, v0, O[dt], 0, 0, 0);
      O[dt] = __builtin_amdgcn_mfma_f32_16x16x32_bf16(pa1, v1, O[dt], 0, 0, 0);
    }
    __builtin_amdgcn_s_setprio(0);
    __syncthreads();         // all LDS reads done + next-tile DMA landed
    cur ^= 1;
  }
  // epilogue: normalize, store bf16 for the out-GEMM
  float inv[4];
#pragma unroll
  for (int r = 0; r < 4; ++r) inv[r] = 1.0f / lreg[r];
#pragma unroll
  for (int dt = 0; dt < 4; ++dt)
#pragma unroll
    for (int r = 0; r < 4; ++r)
      attn[((size_t)(b * T_ + i0 + 16 * w + 4 * g + r)) * 1024 +
           h * 64 + dt * 16 + low] = f2bf(O[dt][r] * inv[r]);
}

// ---------------------------------------------------------------------------
extern "C" void kernel_launch(void* const* d_in, const int* in_sizes, int n_in,
                              void* d_out, int out_size, void* d_ws, size_t ws_size,
                              hipStream_t stream) {
  const float* inputs = (const float*)d_in[0];
  const float* memory = (const float*)d_in[1];
  const float* w_qkv  = (const float*)d_in[2];
  const float* w_pos  = (const float*)d_in[3];
  const float* w_out  = (const float*)d_in[4];
  const float* uvar   = (const float*)d_in[5];
  const float* vvar   = (const float*)d_in[6];
  const float* gamma  = (const float*)d_in[7];
  const float* beta   = (const float*)d_in[8];
  float* out = (float*)d_out;

  // workspace layout, all bf16 (56.6 MB)
  ushort* qkvB = (ushort*)d_ws;                       // 4096*3072
  ushort* xnb  = qkvB + (size_t)4096 * 3072;          // 4096*1024
  ushort* phib = xnb  + (size_t)4096 * 1024;          // 1024*1024
  ushort* RmB  = phib + (size_t)1024 * 1024;          // 1024*1024
  ushort* wqb  = RmB  + (size_t)1024 * 1024;          // 3072*1024
  ushort* wpb  = wqb  + (size_t)3072 * 1024;          // 1024*1024
  ushort* wob  = wpb  + (size_t)1024 * 1024;          // 1024*1024
  ushort* vtg  = wob  + (size_t)1024 * 1024;          // 4096*1024 (V^T)
  ushort* attnb = xnb;                                // reuse after QKV GEMM

  prep_kernel<<<13312, 256, 0, stream>>>(inputs, memory, gamma, beta, xnb,
                                         phib, w_qkv, wqb, w_pos, wpb, w_out, wob);
  qkv_r_gemm<<<832, 256, 0, stream>>>(xnb, wqb, qkvB, phib, wpb, RmB);
  vtrans_kernel<<<B_ * H_ * 16, 256, 0, stream>>>(qkvB, vtg);
  attn_mfma_kernel<<<dim3(B_ * H_ * 8), 256, 0, stream>>>(qkvB, RmB, vtg, uvar, vvar, attnb);
  out_gemm<<<128, 256, 0, stream>>>(attnb, wob, out);
}